// Round 1
// baseline (2359.270 us; speedup 1.0000x reference)
//
#include <hip/hip_runtime.h>
#include <hip/hip_bf16.h>

#define K_DIM 4096
#define N_DIM 11008
#define M_DIM 8192

typedef float f32x4 __attribute__((ext_vector_type(4)));
typedef __bf16 bf16x8 __attribute__((ext_vector_type(8)));

typedef __attribute__((address_space(1))) unsigned int gu32;
typedef __attribute__((address_space(3))) unsigned int lu32;

__device__ __forceinline__ void g2l16(const void* gp, void* lp) {
    __builtin_amdgcn_global_load_lds((gu32*)gp, (lu32*)lp, 16, 0, 0);
}

// ---------------------------------------------------------------------------
// Kernel 1: rowsum[m] = sum_k X[m,k]   (one 256-thread block per row)
// ---------------------------------------------------------------------------
__global__ __launch_bounds__(256) void rowsum_kernel(const float* __restrict__ X,
                                                     float* __restrict__ rs) {
    const int row = blockIdx.x;
    const float4* xr = (const float4*)(X + (size_t)row * K_DIM);
    const int t = threadIdx.x;
    float s = 0.f;
#pragma unroll
    for (int j = 0; j < 4; ++j) {
        float4 v = xr[t + 256 * j];
        s += v.x + v.y + v.z + v.w;
    }
#pragma unroll
    for (int off = 32; off > 0; off >>= 1) s += __shfl_down(s, off);
    __shared__ float part[4];
    if ((t & 63) == 0) part[t >> 6] = s;
    __syncthreads();
    if (t == 0) rs[row] = part[0] + part[1] + part[2] + part[3];
}

// ---------------------------------------------------------------------------
// Kernel 2: 128x128 tile GEMM, BK=32, bf16 MFMA 16x16x32.
//   dot[m,n] = sum_k X[m,k] * q[n,k]   (q exact in bf16, X rounded to bf16)
//   out      = scale[n]*(dot - zp[n]*rowsum[m]) + bias[n]
// W arrives as int32 per harness convention (integer -> const int*).
// ---------------------------------------------------------------------------
__global__ __launch_bounds__(256, 2)
void qlin_gemm(const float* __restrict__ X, const int* __restrict__ Wq,
               const float* __restrict__ scale, const float* __restrict__ zp,
               const float* __restrict__ bias, const float* __restrict__ rowsum,
               float* __restrict__ out) {
    __shared__ float lx[128 * 32];  // 16 KB, row-major [row][k]
    __shared__ int   lw[128 * 32];  // 16 KB, row-major [row][k]

    const int tid = threadIdx.x;
    const int l = tid & 63;
    const int w = tid >> 6;
    const int wave_m = w & 1;
    const int wave_n = w >> 1;
    const int q = l >> 4;
    const int ln = l & 15;

    const int m0 = blockIdx.y * 128;
    const int n0 = blockIdx.x * 128;

    // staging: chunk c covers rows c*32..c*32+31; lane l -> row +w*8+(l>>3), col (l&7)*4
    const float* xg = X + (size_t)(m0 + w * 8 + (l >> 3)) * K_DIM + ((l & 7) * 4);
    const int*   wg = Wq + (size_t)(n0 + w * 8 + (l >> 3)) * K_DIM + ((l & 7) * 4);
    float* lxp = lx + (w * 256 + l * 4);  // byte off = w*1024 + l*16
    int*   lwp = lw + (w * 256 + l * 4);

    f32x4 acc[4][4] = {};

    for (int kt = 0; kt < 128; ++kt) {
        const int k0 = kt * 32;
#pragma unroll
        for (int c = 0; c < 4; ++c) {
            g2l16(xg + (size_t)c * 32 * K_DIM + k0, lxp + c * 1024);
            g2l16(wg + (size_t)c * 32 * K_DIM + k0, lwp + c * 1024);
        }
        __syncthreads();  // drains vmcnt -> LDS tiles ready

        bf16x8 af[4], bfr[4];
#pragma unroll
        for (int i = 0; i < 4; ++i) {
            const f32x4* p = (const f32x4*)(lx + (wave_m * 64 + i * 16 + ln) * 32 + q * 8);
            f32x4 lo = p[0], hi = p[1];
            bf16x8 t;
            t[0] = (__bf16)lo[0]; t[1] = (__bf16)lo[1];
            t[2] = (__bf16)lo[2]; t[3] = (__bf16)lo[3];
            t[4] = (__bf16)hi[0]; t[5] = (__bf16)hi[1];
            t[6] = (__bf16)hi[2]; t[7] = (__bf16)hi[3];
            af[i] = t;
        }
#pragma unroll
        for (int j = 0; j < 4; ++j) {
            const int4* p = (const int4*)(lw + (wave_n * 64 + j * 16 + ln) * 32 + q * 8);
            int4 lo = p[0], hi = p[1];
            bf16x8 t;
            t[0] = (__bf16)(float)lo.x; t[1] = (__bf16)(float)lo.y;
            t[2] = (__bf16)(float)lo.z; t[3] = (__bf16)(float)lo.w;
            t[4] = (__bf16)(float)hi.x; t[5] = (__bf16)(float)hi.y;
            t[6] = (__bf16)(float)hi.z; t[7] = (__bf16)(float)hi.w;
            bfr[j] = t;
        }
#pragma unroll
        for (int i = 0; i < 4; ++i)
#pragma unroll
            for (int j = 0; j < 4; ++j)
                acc[i][j] = __builtin_amdgcn_mfma_f32_16x16x32_bf16(af[i], bfr[j], acc[i][j], 0, 0, 0);
        __syncthreads();  // all LDS reads done before next-iter restage
    }

    // epilogue: y = scale[n]*(dot - zp[n]*rowsum[m]) + bias[n]
    float sc[4], zv[4], bv[4];
    int ncol[4];
#pragma unroll
    for (int j = 0; j < 4; ++j) {
        const int n = n0 + wave_n * 64 + j * 16 + ln;
        ncol[j] = n;
        sc[j] = scale[n];
        zv[j] = zp[n];
        bv[j] = bias[n];
    }
#pragma unroll
    for (int i = 0; i < 4; ++i) {
#pragma unroll
        for (int r = 0; r < 4; ++r) {
            const int m = m0 + wave_m * 64 + i * 16 + q * 4 + r;
            const float rsm = rowsum[m];
            const size_t rowoff = (size_t)m * N_DIM;
#pragma unroll
            for (int j = 0; j < 4; ++j) {
                out[rowoff + ncol[j]] = sc[j] * (acc[i][j][r] - zv[j] * rsm) + bv[j];
            }
        }
    }
}

extern "C" void kernel_launch(void* const* d_in, const int* in_sizes, int n_in,
                              void* d_out, int out_size, void* d_ws, size_t ws_size,
                              hipStream_t stream) {
    const float* X      = (const float*)d_in[0];
    const int*   Wq     = (const int*)d_in[1];   // integer input -> const int*
    const float* scale  = (const float*)d_in[2];
    const float* zp     = (const float*)d_in[3];
    const float* bias   = (const float*)d_in[4];
    float* out = (float*)d_out;
    float* rowsum = (float*)d_ws;  // 8192 floats = 32 KB scratch

    rowsum_kernel<<<M_DIM, 256, 0, stream>>>(X, rowsum);

    dim3 grid(N_DIM / 128, M_DIM / 128);  // (86, 64)
    qlin_gemm<<<grid, 256, 0, stream>>>(X, Wq, scale, zp, bias, rowsum, out);
}

// Round 2
// 1857.503 us; speedup vs baseline: 1.2701x; 1.2701x over previous
//
#include <hip/hip_runtime.h>
#include <hip/hip_bf16.h>

#define K_DIM 4096
#define N_DIM 11008
#define M_DIM 8192

typedef _Float16 f16;
typedef f16 f16x4 __attribute__((ext_vector_type(4)));
typedef f16 f16x8 __attribute__((ext_vector_type(8)));
typedef float f32x4 __attribute__((ext_vector_type(4)));

typedef __attribute__((address_space(1))) unsigned int gu32;
typedef __attribute__((address_space(3))) unsigned int lu32;

__device__ __forceinline__ void g2l16(const void* gp, void* lp) {
    __builtin_amdgcn_global_load_lds((gu32*)gp, (lu32*)lp, 16, 0, 0);
}

// ---------------------------------------------------------------------------
// Prepass 1: W int32 -> f16 (int8 values are exact in f16)
// ---------------------------------------------------------------------------
__global__ __launch_bounds__(256) void convw_kernel(const int* __restrict__ Wq,
                                                    f16* __restrict__ Wh) {
    const size_t n4 = (size_t)N_DIM * K_DIM / 4;  // 11,272,192 int4 groups
    const size_t stride = (size_t)gridDim.x * 256;
    const int4* src = (const int4*)Wq;
    f16x4* dst = (f16x4*)Wh;
    for (size_t i = (size_t)blockIdx.x * 256 + threadIdx.x; i < n4; i += stride) {
        int4 a = src[i];
        f16x4 o = {(f16)a.x, (f16)a.y, (f16)a.z, (f16)a.w};
        dst[i] = o;
    }
}

// ---------------------------------------------------------------------------
// Prepass 2: X f32 -> f16, plus rowsum of the CONVERTED values (consistency
// with the zp correction term). One 256-thread block per row.
// ---------------------------------------------------------------------------
__global__ __launch_bounds__(256) void convx_kernel(const float* __restrict__ X,
                                                    f16* __restrict__ Xh,
                                                    float* __restrict__ rs) {
    const int row = blockIdx.x;
    const int t = threadIdx.x;
    const float4* xr = (const float4*)(X + (size_t)row * K_DIM);
    f16x4* xo = (f16x4*)(Xh + (size_t)row * K_DIM);
    float s = 0.f;
#pragma unroll
    for (int j = 0; j < 4; ++j) {
        float4 v = xr[t + 256 * j];
        f16x4 h = {(f16)v.x, (f16)v.y, (f16)v.z, (f16)v.w};
        xo[t + 256 * j] = h;
        s += (float)h[0] + (float)h[1] + (float)h[2] + (float)h[3];
    }
#pragma unroll
    for (int off = 32; off > 0; off >>= 1) s += __shfl_down(s, off);
    __shared__ float part[4];
    if ((t & 63) == 0) part[t >> 6] = s;
    __syncthreads();
    if (t == 0) rs[row] = part[0] + part[1] + part[2] + part[3];
}

// ---------------------------------------------------------------------------
// GEMM: 128x128 tile, BK=32, f16 MFMA 16x16x32, m97 structure.
// LDS rows are 64 B = 4 groups of 16 B. XOR swizzle: logical group g of row r
// is stored at physical slot g ^ ((r>>1)&3). global_load_lds forces LDS dest
// = base + lane*16, so the swizzle is applied on the GLOBAL address side:
// lane l fetches logical group (l&3) ^ ((l>>3)&3) of its row. Reads of
// logical group q use physical slot q ^ ((ln>>1)&3) -> 2 lanes/bank (free).
//   y[m,n] = scale[n]*(dot[m,n] - zp[n]*rowsum[m]) + bias[n]
// ---------------------------------------------------------------------------
__global__ __launch_bounds__(256, 2)
void qlin_gemm(const f16* __restrict__ Xh, const f16* __restrict__ Wh,
               const float* __restrict__ scale, const float* __restrict__ zp,
               const float* __restrict__ bias, const float* __restrict__ rowsum,
               float* __restrict__ out) {
    __shared__ char lx[8192];  // 128 rows x 64 B (32 f16)
    __shared__ char lw[8192];

    const int tid = threadIdx.x;
    const int l = tid & 63;
    const int w = tid >> 6;
    const int wm = w & 1;
    const int wn = w >> 1;
    const int q = l >> 4;
    const int ln = l & 15;

    const int m0 = blockIdx.y * 128;
    const int n0 = blockIdx.x * 128;

    const int sg = (l & 3) ^ ((l >> 3) & 3);  // staging logical group (lane-const)
    const size_t rowbytes = K_DIM * 2;

    // wave w, round c stages rows c*64 + w*16 + (l>>2); c handled by +64-row offset
    const char* xg = (const char*)Xh + (size_t)(m0 + w * 16 + (l >> 2)) * rowbytes + sg * 16;
    const char* wg = (const char*)Wh + (size_t)(n0 + w * 16 + (l >> 2)) * rowbytes + sg * 16;
    char* lxp = lx + w * 1024 + l * 16;
    char* lwp = lw + w * 1024 + l * 16;

    const int rsw = (q ^ ((ln >> 1) & 3)) * 16;  // read slot byte offset (lane-const)
    const char* lxr = lx + (wm * 64 + ln) * 64 + rsw;
    const char* lwr = lw + (wn * 64 + ln) * 64 + rsw;

    f32x4 acc[4][4] = {};

    for (int kt = 0; kt < 128; ++kt) {
        const size_t k0 = (size_t)kt * 64;  // bytes into the row
        g2l16(xg + k0, lxp);
        g2l16(xg + 64 * rowbytes + k0, lxp + 4096);
        g2l16(wg + k0, lwp);
        g2l16(wg + 64 * rowbytes + k0, lwp + 4096);
        __syncthreads();  // vmcnt(0) drain -> tiles ready

        f16x8 af[4], bf[4];
#pragma unroll
        for (int i = 0; i < 4; ++i) af[i] = *(const f16x8*)(lxr + i * 1024);
#pragma unroll
        for (int j = 0; j < 4; ++j) bf[j] = *(const f16x8*)(lwr + j * 1024);
#pragma unroll
        for (int i = 0; i < 4; ++i)
#pragma unroll
            for (int j = 0; j < 4; ++j)
                acc[i][j] = __builtin_amdgcn_mfma_f32_16x16x32_f16(af[i], bf[j], acc[i][j], 0, 0, 0);
        __syncthreads();  // all reads done before next restage
    }

    // epilogue
    float sc[4], zv[4], bv[4];
    int ncol[4];
#pragma unroll
    for (int j = 0; j < 4; ++j) {
        const int n = n0 + wn * 64 + j * 16 + ln;
        ncol[j] = n;
        sc[j] = scale[n];
        zv[j] = zp[n];
        bv[j] = bias[n];
    }
#pragma unroll
    for (int i = 0; i < 4; ++i) {
#pragma unroll
        for (int r = 0; r < 4; ++r) {
            const int m = m0 + wm * 64 + i * 16 + q * 4 + r;
            const float rsm = rowsum[m];
            const size_t rowoff = (size_t)m * N_DIM;
#pragma unroll
            for (int j = 0; j < 4; ++j) {
                out[rowoff + ncol[j]] = sc[j] * (acc[i][j][r] - zv[j] * rsm) + bv[j];
            }
        }
    }
}

extern "C" void kernel_launch(void* const* d_in, const int* in_sizes, int n_in,
                              void* d_out, int out_size, void* d_ws, size_t ws_size,
                              hipStream_t stream) {
    const float* X     = (const float*)d_in[0];
    const int*   Wq    = (const int*)d_in[1];
    const float* scale = (const float*)d_in[2];
    const float* zp    = (const float*)d_in[3];
    const float* bias  = (const float*)d_in[4];
    float* out = (float*)d_out;

    // ws layout: Wh (90,177,536 B) | Xh (67,108,864 B) | rowsum (32 KB)
    f16* Wh = (f16*)d_ws;
    f16* Xh = (f16*)((char*)d_ws + (size_t)N_DIM * K_DIM * 2);
    float* rowsum = (float*)((char*)d_ws + (size_t)N_DIM * K_DIM * 2 + (size_t)M_DIM * K_DIM * 2);

    convw_kernel<<<4096, 256, 0, stream>>>(Wq, Wh);
    convx_kernel<<<M_DIM, 256, 0, stream>>>(X, Xh, rowsum);

    dim3 grid(N_DIM / 128, M_DIM / 128);  // (86, 64)
    qlin_gemm<<<grid, 256, 0, stream>>>(Xh, Wh, scale, zp, bias, rowsum, out);
}